// Round 1
// baseline (7569.262 us; speedup 1.0000x reference)
//
#include <hip/hip_runtime.h>

#define S_LEN 8192
#define DIN 120
#define HID 64
#define G4 256
#define NOUT 10
#define DHPM 258

// ---------------- workspace layout (float offsets) ----------------
static constexpr size_t OFF_PRE0 = 0;                                  // [S][256]
static constexpr size_t OFF_ACT0 = OFF_PRE0 + (size_t)S_LEN * G4;      // [S][256] activated gates L0
static constexpr size_t OFF_ACT1 = OFF_ACT0 + (size_t)S_LEN * G4;      // [S][256] activated gates L1
static constexpr size_t OFF_H0S  = OFF_ACT1 + (size_t)S_LEN * G4;      // [S+1][64]  row t+1 = h0 after step t, row0 = 0
static constexpr size_t OFF_C0S  = OFF_H0S + (size_t)(S_LEN + 1) * HID;
static constexpr size_t OFF_H1S  = OFF_C0S + (size_t)(S_LEN + 1) * HID; // [S+2][64] row t+2 = h1 after step t
static constexpr size_t OFF_C1S  = OFF_H1S + (size_t)(S_LEN + 2) * HID;
static constexpr size_t OFF_GOH  = OFF_C1S + (size_t)(S_LEN + 2) * HID; // [S][64]
static constexpr size_t OFF_GWS  = OFF_GOH + (size_t)S_LEN * HID;       // [S][120]
static constexpr size_t OFF_PMN  = OFF_GWS + (size_t)S_LEN * DIN;       // [2][64][64]
static constexpr size_t OFF_PMX  = OFF_PMN + 2 * 64 * 64;
static constexpr size_t OFF_MN   = OFF_PMX + 2 * 64 * 64;               // [2][64]
static constexpr size_t OFF_INV  = OFF_MN + 128;                        // [2][64]
static constexpr size_t OFF_WSUM = OFF_INV + 128;                       // [64]
static constexpr size_t OFF_S2   = OFF_WSUM + 64;                       // [2]

__device__ __forceinline__ float sig_(float x)  { return 1.0f / (1.0f + __expf(-x)); }
__device__ __forceinline__ float tanh_(float x) { return 1.0f - 2.0f / (__expf(2.0f * x) + 1.0f); }

// ---------------- prep: wsum = colsum(Wlin), s2 = colsum(Whpm2) ----------------
__global__ __launch_bounds__(128) void wl_prep_kernel(const float* __restrict__ Wlin,
                                                      const float* __restrict__ Whpm2,
                                                      float* __restrict__ ws) {
  int i = threadIdx.x;
  if (i < HID) {
    float s = 0.0f;
    for (int o = 0; o < NOUT; ++o) s += Wlin[o * HID + i];
    ws[OFF_WSUM + i] = s;
  } else if (i < HID + 2) {
    int h = i - HID;
    float s = 0.0f;
    for (int d = 0; d < DIN; ++d) s += Whpm2[d * 2 + h];
    ws[OFF_S2 + h] = s;
  }
}

// ---------------- pre0 = input @ Wih0.T + bih0 + bhh0 (8 timesteps per block) ----------------
__global__ __launch_bounds__(256) void wl_pre0_kernel(const float* __restrict__ input,
                                                      const float* __restrict__ Wih0,
                                                      const float* __restrict__ bih0,
                                                      const float* __restrict__ bhh0,
                                                      float* __restrict__ ws) {
  __shared__ __align__(16) float xin[8 * DIN];
  int tid = threadIdx.x;
  size_t t0 = (size_t)blockIdx.x * 8;
  for (int idx = tid; idx < 8 * DIN; idx += 256) xin[idx] = input[t0 * DIN + idx];
  float4 w[30];
  const float4* wr = (const float4*)(Wih0 + (size_t)tid * DIN);
#pragma unroll
  for (int i = 0; i < 30; ++i) w[i] = wr[i];
  float b = bih0[tid] + bhh0[tid];
  __syncthreads();
#pragma unroll
  for (int tt = 0; tt < 8; ++tt) {
    const float4* x4 = (const float4*)(xin + tt * DIN);
    float acc = b;
#pragma unroll
    for (int i = 0; i < 30; ++i) {
      float4 x = x4[i];
      acc += w[i].x * x.x + w[i].y * x.y + w[i].z * x.z + w[i].w * x.w;
    }
    ws[OFF_PRE0 + (t0 + tt) * G4 + tid] = acc;
  }
}

// ---------------- sequential scan: layer0 at superstep s computes h0[s]; layer1 lags one ----------------
__global__ __launch_bounds__(512) void wl_scan_kernel(const float* __restrict__ Whh0,
                                                      const float* __restrict__ Wih1,
                                                      const float* __restrict__ Whh1,
                                                      const float* __restrict__ bih1,
                                                      const float* __restrict__ bhh1,
                                                      float* __restrict__ ws) {
  __shared__ __align__(16) float h0_lds[HID];
  __shared__ __align__(16) float h1_lds[HID];
  __shared__ float a0_lds[G4];
  __shared__ float a1_lds[G4];
  float* ACT0 = ws + OFF_ACT0;
  float* ACT1 = ws + OFF_ACT1;
  float* H0S = ws + OFF_H0S;
  float* C0S = ws + OFF_C0S;
  float* H1S = ws + OFF_H1S;
  float* C1S = ws + OFF_C1S;
  const float* PRE0 = ws + OFF_PRE0;
  int tid = threadIdx.x;
  float4 wa[16], wb[16];
  float b1 = 0.0f;
  if (tid < G4) {
    const float4* W = (const float4*)(Whh0 + (size_t)tid * HID);
#pragma unroll
    for (int i = 0; i < 16; ++i) wa[i] = W[i];
  } else {
    int j = tid - G4;
    const float4* Wi = (const float4*)(Wih1 + (size_t)j * HID);
    const float4* Wh = (const float4*)(Whh1 + (size_t)j * HID);
#pragma unroll
    for (int i = 0; i < 16; ++i) { wa[i] = Wi[i]; wb[i] = Wh[i]; }
    b1 = bih1[j] + bhh1[j];
  }
  float c0 = 0.0f, c1 = 0.0f;
  if (tid < HID) {
    h0_lds[tid] = 0.0f;
    h1_lds[tid] = 0.0f;
    H0S[tid] = 0.0f; C0S[tid] = 0.0f;
    H1S[tid] = 0.0f; H1S[HID + tid] = 0.0f;
    C1S[tid] = 0.0f; C1S[HID + tid] = 0.0f;
  }
  __syncthreads();
  float pre_n = (tid < G4) ? PRE0[tid] : 0.0f;
  for (int s = 0; s <= S_LEN; ++s) {
    if (tid < G4) {
      if (s < S_LEN) {
        float acc = pre_n;
        if (s + 1 < S_LEN) pre_n = PRE0[(size_t)(s + 1) * G4 + tid];  // prefetch next step
        const float4* h4 = (const float4*)h0_lds;
#pragma unroll
        for (int i = 0; i < 16; ++i) {
          float4 h = h4[i];
          acc += wa[i].x * h.x + wa[i].y * h.y + wa[i].z * h.z + wa[i].w * h.w;
        }
        float a = (tid >= 128 && tid < 192) ? tanh_(acc) : sig_(acc);
        a0_lds[tid] = a;
        ACT0[(size_t)s * G4 + tid] = a;
      }
    } else {
      if (s >= 1) {
        int j = tid - G4;
        int t = s - 1;
        float acc = b1;
        const float4* h4 = (const float4*)h0_lds;  // = h0[t]
        const float4* g4 = (const float4*)h1_lds;  // = h1[t-1]
#pragma unroll
        for (int i = 0; i < 16; ++i) {
          float4 h = h4[i];
          acc += wa[i].x * h.x + wa[i].y * h.y + wa[i].z * h.z + wa[i].w * h.w;
        }
#pragma unroll
        for (int i = 0; i < 16; ++i) {
          float4 h = g4[i];
          acc += wb[i].x * h.x + wb[i].y * h.y + wb[i].z * h.z + wb[i].w * h.w;
        }
        float a = (j >= 128 && j < 192) ? tanh_(acc) : sig_(acc);
        a1_lds[j] = a;
        ACT1[(size_t)t * G4 + j] = a;
      }
    }
    __syncthreads();
    if (tid < HID) {
      if (s < S_LEN) {
        float i_ = a0_lds[tid], f_ = a0_lds[HID + tid], g_ = a0_lds[2 * HID + tid], o_ = a0_lds[3 * HID + tid];
        c0 = f_ * c0 + i_ * g_;
        float h = o_ * tanh_(c0);
        h0_lds[tid] = h;
        H0S[(size_t)(s + 1) * HID + tid] = h;
        C0S[(size_t)(s + 1) * HID + tid] = c0;
      }
    } else if (tid >= G4 && tid < G4 + HID) {
      if (s >= 1) {
        int k = tid - G4;
        int t = s - 1;
        float i_ = a1_lds[k], f_ = a1_lds[HID + k], g_ = a1_lds[2 * HID + k], o_ = a1_lds[3 * HID + k];
        c1 = f_ * c1 + i_ * g_;
        float h = o_ * tanh_(c1);
        h1_lds[k] = h;
        H1S[(size_t)(t + 2) * HID + k] = h;
        C1S[(size_t)(t + 2) * HID + k] = c1;
      }
    }
    __syncthreads();
  }
}

// ---------------- per-t gradient (fully parallel; uses stored activations only) ----------------
__global__ __launch_bounds__(256) void wl_grad_kernel(const float* __restrict__ Wih0,
                                                      const float* __restrict__ Whh0,
                                                      const float* __restrict__ Wih1,
                                                      const float* __restrict__ Whh1,
                                                      float* __restrict__ ws) {
  int t = blockIdx.x;
  int tid = threadIdx.x;
  float* GOH = ws + OFF_GOH;
  float* GWS = ws + OFF_GWS;
  if (t == 0) {  // gohs[0]=0, gws[0]=0
    if (tid < HID) GOH[tid] = 0.0f;
    if (tid < DIN) GWS[tid] = 0.0f;
    return;
  }
  const float* ACT0 = ws + OFF_ACT0;
  const float* ACT1 = ws + OFF_ACT1;
  const float* C0S = ws + OFF_C0S;
  const float* C1S = ws + OFF_C1S;
  __shared__ float a3[G4], am[G4], a0[G4];
  __shared__ float dg3[G4], dg0[G4], dgm[G4];
  __shared__ float dh0n[HID], dh1m[HID], dc1m[HID];
  __shared__ float cbuf[5 * HID];  // c3 | c1m | c1pp | c0n | c0p
  __shared__ float wsum_s[HID];
  a3[tid] = ACT1[(size_t)t * G4 + tid];
  am[tid] = ACT1[(size_t)(t - 1) * G4 + tid];
  a0[tid] = ACT0[(size_t)t * G4 + tid];
  if (tid < HID) {
    cbuf[tid]           = C1S[(size_t)(t + 2) * HID + tid];  // c3  = c1[t]
    cbuf[HID + tid]     = C1S[(size_t)(t + 1) * HID + tid];  // c1m = c1[t-1]
    cbuf[2 * HID + tid] = C1S[(size_t)t * HID + tid];        // c1pp= c1[t-2]
    cbuf[3 * HID + tid] = C0S[(size_t)(t + 1) * HID + tid];  // c0n = c0[t]
    cbuf[4 * HID + tid] = C0S[(size_t)t * HID + tid];        // c0p = c0[t-1]
    wsum_s[tid] = ws[OFF_WSUM + tid];
  }
  __syncthreads();
  // backward through cell3 (== real layer-1 cell at step t)
  if (tid < HID) {
    int k = tid;
    float tc = tanh_(cbuf[k]);
    float si = a3[k], sf = a3[HID + k], tg = a3[2 * HID + k], so = a3[3 * HID + k];
    float dh = wsum_s[k];
    float dov = dh * tc * so * (1.0f - so);
    float dc = dh * so * (1.0f - tc * tc);
    dg3[k] = dc * tg * si * (1.0f - si);
    dg3[HID + k] = dc * cbuf[HID + k] * sf * (1.0f - sf);
    dg3[2 * HID + k] = dc * si * (1.0f - tg * tg);
    dg3[3 * HID + k] = dov;
    dc1m[k] = dc * sf;
  }
  __syncthreads();
  // dh0n = dg3 @ Wih1 ; dh1m = dg3 @ Whh1
  if (tid < HID) {
    float s = 0.0f;
#pragma unroll 8
    for (int j = 0; j < G4; ++j) s += dg3[j] * Wih1[(size_t)j * HID + tid];
    dh0n[tid] = s;
  } else if (tid < 2 * HID) {
    int k = tid - HID;
    float s = 0.0f;
#pragma unroll 8
    for (int j = 0; j < G4; ++j) s += dg3[j] * Whh1[(size_t)j * HID + k];
    dh1m[k] = s;
  }
  __syncthreads();
  // backward through cell0 (dc0n = 0) and cellm (== layer-1 cell at step t-1)
  if (tid < HID) {
    int k = tid;
    float tc = tanh_(cbuf[3 * HID + k]);
    float si = a0[k], sf = a0[HID + k], tg = a0[2 * HID + k], so = a0[3 * HID + k];
    float dh = dh0n[k];
    float dov = dh * tc * so * (1.0f - so);
    float dc = dh * so * (1.0f - tc * tc);
    dg0[k] = dc * tg * si * (1.0f - si);
    dg0[HID + k] = dc * cbuf[4 * HID + k] * sf * (1.0f - sf);
    dg0[2 * HID + k] = dc * si * (1.0f - tg * tg);
    dg0[3 * HID + k] = dov;
  } else if (tid < 2 * HID) {
    int k = tid - HID;
    float tc = tanh_(cbuf[HID + k]);
    float si = am[k], sf = am[HID + k], tg = am[2 * HID + k], so = am[3 * HID + k];
    float dh = dh1m[k];
    float dov = dh * tc * so * (1.0f - so);
    float dc = dh * so * (1.0f - tc * tc) + dc1m[k];
    dgm[k] = dc * tg * si * (1.0f - si);
    dgm[HID + k] = dc * cbuf[2 * HID + k] * sf * (1.0f - sf);
    dgm[2 * HID + k] = dc * si * (1.0f - tg * tg);
    dgm[3 * HID + k] = dov;
  }
  __syncthreads();
  // gws = dg0 @ Wih0 ; gohs = dg0 @ Whh0 + dgm @ Wih1
  if (tid < DIN) {
    float s = 0.0f;
#pragma unroll 8
    for (int j = 0; j < G4; ++j) s += dg0[j] * Wih0[(size_t)j * DIN + tid];
    GWS[(size_t)t * DIN + tid] = s;
  } else if (tid < DIN + HID) {
    int k = tid - DIN;
    float sA = 0.0f, sB = 0.0f;
#pragma unroll 8
    for (int j = 0; j < G4; ++j) {
      sA += dg0[j] * Whh0[(size_t)j * HID + k];
      sB += dgm[j] * Wih1[(size_t)j * HID + k];
    }
    GOH[(size_t)t * HID + k] = sA + sB;
  }
}

// ---------------- outs[t] = Wlin @ h1[t] + blin ----------------
__global__ __launch_bounds__(256) void wl_outs_kernel(const float* __restrict__ Wlin,
                                                      const float* __restrict__ blin,
                                                      const float* __restrict__ ws,
                                                      float* __restrict__ out) {
  int tloc = threadIdx.x >> 5, o = threadIdx.x & 31;
  int t = blockIdx.x * 8 + tloc;
  if (o < NOUT) {
    const float* h1 = ws + OFF_H1S + (size_t)(t + 2) * HID;
    const float* wr = Wlin + o * HID;
    float s = blin[o];
#pragma unroll 8
    for (int k = 0; k < HID; ++k) s += wr[k] * h1[k];
    out[(size_t)t * NOUT + o] = s;
  }
}

// ---------------- column-wise min/max partials for gohs (m=0) and old_hts (m=1) ----------------
__global__ __launch_bounds__(256) void wl_mm_partial_kernel(float* __restrict__ ws) {
  int m = blockIdx.y;
  int col = threadIdx.x & 63, rg = threadIdx.x >> 6;
  const float* src = ws + (m == 0 ? OFF_GOH : OFF_H0S);  // H0S rows 0..8191 == old_hts
  float mn = 3.4e38f, mx = -3.4e38f;
  int r0 = blockIdx.x * 128;
  for (int r = r0 + rg; r < r0 + 128; r += 4) {
    float v = src[(size_t)r * HID + col];
    mn = fminf(mn, v);
    mx = fmaxf(mx, v);
  }
  __shared__ float smn[256], smx[256];
  smn[threadIdx.x] = mn;
  smx[threadIdx.x] = mx;
  __syncthreads();
  if (threadIdx.x < 64) {
    float a = fminf(fminf(smn[col], smn[64 + col]), fminf(smn[128 + col], smn[192 + col]));
    float b = fmaxf(fmaxf(smx[col], smx[64 + col]), fmaxf(smx[128 + col], smx[192 + col]));
    ws[OFF_PMN + ((size_t)m * 64 + blockIdx.x) * 64 + col] = a;
    ws[OFF_PMX + ((size_t)m * 64 + blockIdx.x) * 64 + col] = b;
  }
}

__global__ __launch_bounds__(128) void wl_mm_final_kernel(float* __restrict__ ws) {
  int i = threadIdx.x;
  if (i < 128) {
    int m = i >> 6, col = i & 63;
    float mn = 3.4e38f, mx = -3.4e38f;
    for (int b = 0; b < 64; ++b) {
      mn = fminf(mn, ws[OFF_PMN + ((size_t)m * 64 + b) * 64 + col]);
      mx = fmaxf(mx, ws[OFF_PMX + ((size_t)m * 64 + b) * 64 + col]);
    }
    ws[OFF_MN + i] = mn;
    ws[OFF_INV + i] = 1.0f / (mx - mn + 1e-6f);
  }
}

// ---------------- final: output_data assembly + HPM fwd + F + AllF_x ----------------
__global__ __launch_bounds__(256) void wl_final_kernel(const float* __restrict__ input,
                                                       const float* __restrict__ Whpm1,
                                                       const float* __restrict__ bhpm1,
                                                       const float* __restrict__ Whpm2,
                                                       const float* __restrict__ bhpm2,
                                                       const float* __restrict__ ws,
                                                       float* __restrict__ out) {
  int t = blockIdx.x;
  int tid = threadIdx.x;
  __shared__ float od[DHPM];
  __shared__ float red[256];
  __shared__ float zb[4];
  const float* GOH = ws + OFF_GOH;
  const float* H0S = ws + OFF_H0S;
  const float* MNp = ws + OFF_MN;
  const float* INVp = ws + OFF_INV;
  if (tid < NOUT) {
    od[tid] = out[(size_t)t * NOUT + tid];
  } else if (tid < 74) {
    int k = tid - 10;
    od[tid] = (GOH[(size_t)t * HID + k] - MNp[k]) * INVp[k];
  } else if (tid < 194) {
    int q = tid - 74;
    od[tid] = input[(size_t)t * DIN + q];
  } else {
    int k = tid - 194;
    od[tid] = (H0S[(size_t)t * HID + k] - MNp[64 + k]) * INVp[64 + k];
  }
  if (tid < 2) {
    int k = 62 + tid;
    od[256 + tid] = (H0S[(size_t)t * HID + k] - MNp[64 + k]) * INVp[64 + k];
  }
  __syncthreads();
  // z1pre[0]
  float p = od[tid] * Whpm1[tid];
  if (tid < 2) p += od[256 + tid] * Whpm1[256 + tid];
  red[tid] = p;
  __syncthreads();
  for (int off = 128; off > 0; off >>= 1) {
    if (tid < off) red[tid] += red[tid + off];
    __syncthreads();
  }
  if (tid == 0) zb[0] = red[0];
  __syncthreads();
  // z1pre[1]
  p = od[tid] * Whpm1[DHPM + tid];
  if (tid < 2) p += od[256 + tid] * Whpm1[DHPM + 256 + tid];
  red[tid] = p;
  __syncthreads();
  for (int off = 128; off > 0; off >>= 1) {
    if (tid < off) red[tid] += red[tid + off];
    __syncthreads();
  }
  if (tid == 0) {
    float z0 = tanh_(zb[0] + bhpm1[0]);
    float z1 = tanh_(red[0] + bhpm1[1]);
    zb[0] = z0;
    zb[1] = z1;
    zb[2] = ws[OFF_S2 + 0] * (1.0f - z0 * z0);
    zb[3] = ws[OFF_S2 + 1] * (1.0f - z1 * z1);
  }
  __syncthreads();
  float z0 = zb[0], z1 = zb[1], d0 = zb[2], d1 = zb[3];
  if (tid < DIN) {
    float G = bhpm2[tid] + z0 * Whpm2[tid * 2] + z1 * Whpm2[tid * 2 + 1];
    out[(size_t)S_LEN * NOUT + (size_t)t * DIN + tid] = ws[OFF_GWS + (size_t)t * DIN + tid] - G;
  }
  out[(size_t)S_LEN * (NOUT + DIN) + (size_t)t * DHPM + tid] = -(d0 * Whpm1[tid] + d1 * Whpm1[DHPM + tid]);
  if (tid < 2) {
    int i2 = 256 + tid;
    out[(size_t)S_LEN * (NOUT + DIN) + (size_t)t * DHPM + i2] = -(d0 * Whpm1[i2] + d1 * Whpm1[DHPM + i2]);
  }
}

extern "C" void kernel_launch(void* const* d_in, const int* in_sizes, int n_in,
                              void* d_out, int out_size, void* d_ws, size_t ws_size,
                              hipStream_t stream) {
  const float* input = (const float*)d_in[0];
  const float* Wih0 = (const float*)d_in[1];
  const float* Whh0 = (const float*)d_in[2];
  const float* bih0 = (const float*)d_in[3];
  const float* bhh0 = (const float*)d_in[4];
  const float* Wih1 = (const float*)d_in[5];
  const float* Whh1 = (const float*)d_in[6];
  const float* bih1 = (const float*)d_in[7];
  const float* bhh1 = (const float*)d_in[8];
  const float* Wlin = (const float*)d_in[9];
  const float* blin = (const float*)d_in[10];
  const float* Whpm1 = (const float*)d_in[11];
  const float* bhpm1 = (const float*)d_in[12];
  const float* Whpm2 = (const float*)d_in[13];
  const float* bhpm2 = (const float*)d_in[14];
  float* ws = (float*)d_ws;
  float* out = (float*)d_out;

  wl_prep_kernel<<<1, 128, 0, stream>>>(Wlin, Whpm2, ws);
  wl_pre0_kernel<<<S_LEN / 8, 256, 0, stream>>>(input, Wih0, bih0, bhh0, ws);
  wl_scan_kernel<<<1, 512, 0, stream>>>(Whh0, Wih1, Whh1, bih1, bhh1, ws);
  wl_grad_kernel<<<S_LEN, 256, 0, stream>>>(Wih0, Whh0, Wih1, Whh1, ws);
  wl_outs_kernel<<<S_LEN / 8, 256, 0, stream>>>(Wlin, blin, ws, out);
  wl_mm_partial_kernel<<<dim3(64, 2), 256, 0, stream>>>(ws);
  wl_mm_final_kernel<<<1, 128, 0, stream>>>(ws);
  wl_final_kernel<<<S_LEN, 256, 0, stream>>>(input, Whpm1, bhpm1, Whpm2, bhpm2, ws, out);
}